// Round 1
// baseline (233.236 us; speedup 1.0000x reference)
//
#include <hip/hip_runtime.h>

// TranslationLayer: out[b,i,j] = in[b, i+dy[b], j-dx[b]] if in-bounds else 0
// B,H,W,C = 128,512,512,1  fp32.  Pure memory-bound shift-gather.
//
// Layout choice: one thread per float4 of output (aligned 16B store).
// Source row offset is constant per row -> reads coalesced even though
// base is only dword-aligned; 4 scalar dword loads per lane.

#define TB 128
#define TH 512
#define TW 512

__global__ __launch_bounds__(256) void TranslationLayer_63350767616318_kernel(
    const float* __restrict__ in,
    const int*   __restrict__ dx,
    const int*   __restrict__ dy,
    float*       __restrict__ out)
{
    const int idx = blockIdx.x * blockDim.x + threadIdx.x;   // float4 index
    // W/4 = 128 (mask 127, shift 7); H = 512 (mask 511, shift 9)
    const int j4   = idx & 127;
    const int rest = idx >> 7;
    const int i    = rest & 511;
    const int b    = rest >> 9;

    const int dyb = dy[b];
    const int dxb = dx[b];
    const int si  = i + dyb;

    float4 v;
    v.x = 0.f; v.y = 0.f; v.z = 0.f; v.w = 0.f;

    if (si >= 0 && si < TH) {
        const float* __restrict__ row = in + ((size_t)(b * TH + si)) * TW;
        const int j0 = (j4 << 2) - dxb;   // source column of element 0
#pragma unroll
        for (int k = 0; k < 4; ++k) {
            const int sj = j0 + k;
            const float val = (sj >= 0 && sj < TW) ? row[sj] : 0.f;
            ((float*)&v)[k] = val;
        }
    }
    ((float4*)out)[idx] = v;
}

extern "C" void kernel_launch(void* const* d_in, const int* in_sizes, int n_in,
                              void* d_out, int out_size, void* d_ws, size_t ws_size,
                              hipStream_t stream)
{
    const float* in = (const float*)d_in[0];
    const int*   dx = (const int*)d_in[1];
    const int*   dy = (const int*)d_in[2];
    float*       out = (float*)d_out;

    // total float4s = 128*512*512/4 = 8,388,608 ; /256 threads = 32768 blocks
    const int total4 = TB * TH * (TW / 4);
    dim3 grid(total4 / 256), block(256);
    TranslationLayer_63350767616318_kernel<<<grid, block, 0, stream>>>(in, dx, dy, out);
}

// Round 3
// 231.098 us; speedup vs baseline: 1.0093x; 1.0093x over previous
//
#include <hip/hip_runtime.h>

// TranslationLayer: out[b,i,j] = in[b, i+dy[b], j-dx[b]] if in-bounds else 0
// B,H,W,C = 128,512,512,1 fp32. Pure memory-bound shift-gather.
//
// R1 -> R2/R3: one aligned dwordx4 load per lane (consecutive lanes,
// fully-packed cache lines) + cross-lane shuffle for the neighbor group +
// wave-uniform funnel shift by (-dx)&3. dx/dy are wave-uniform (a wave spans
// half a row of one sample). Aligned 4-float groups are fully in- or
// out-of-range, so element-level zero-fill reduces to group-level zero-fill.
// R3 fix: __builtin_nontemporal_store requires a NATIVE vector type, not
// HIP's float4 class -> use ext_vector_type(4) float throughout.

#define TB 128
#define TH 512
#define TW 512
#define W4 (TW / 4)   // 128 float4 groups per row

typedef float f4 __attribute__((ext_vector_type(4)));

__global__ __launch_bounds__(256) void TranslationLayer_63350767616318_kernel(
    const float* __restrict__ in,
    const int*   __restrict__ dx,
    const int*   __restrict__ dy,
    float*       __restrict__ out)
{
    const int idx  = blockIdx.x * blockDim.x + threadIdx.x;  // output float4 id
    const int j4   = idx & (W4 - 1);
    const int rest = idx >> 7;        // W4 = 128 -> shift 7
    const int i    = rest & (TH - 1); // TH = 512 -> mask 511
    const int b    = rest >> 9;

    const int dxb = dx[b];
    const int si  = i + dy[b];

    f4 res = (f4)(0.f);

    if (si >= 0 && si < TH) {   // wave-uniform (whole wave same row)
        const f4* __restrict__ row4 =
            (const f4*)(in + ((size_t)(b * TH + si)) * TW);
        const int t = -dxb;
        const int q = t >> 2;   // wave-uniform group offset
        const int r = t & 3;    // wave-uniform residue
        const int a = j4 + q;   // source group for this lane

        f4 v0 = (f4)(0.f);
        if ((unsigned)a < (unsigned)W4) v0 = row4[a];

        if (r == 0) {
            res = v0;           // fast path: shift is a multiple of 4 floats
        } else {
            // neighbor group A[a+1] == lane(i+1)'s v0 (already zero-masked)
            f4 v1;
            v1.x = __shfl_down(v0.x, 1);
            v1.y = __shfl_down(v0.y, 1);
            v1.z = __shfl_down(v0.z, 1);
            v1.w = __shfl_down(v0.w, 1);
            if ((threadIdx.x & 63) == 63) {  // last lane: no neighbor in wave
                v1 = (f4)(0.f);
                if ((unsigned)(a + 1) < (unsigned)W4) v1 = row4[a + 1];
            }
            f4 o;
            if (r == 1)      { o.x = v0.y; o.y = v0.z; o.z = v0.w; o.w = v1.x; }
            else if (r == 2) { o.x = v0.z; o.y = v0.w; o.z = v1.x; o.w = v1.y; }
            else             { o.x = v0.w; o.y = v1.x; o.z = v1.y; o.w = v1.z; }
            res = o;
        }
    }
    // output is never re-read: nontemporal store
    __builtin_nontemporal_store(res, (f4*)out + idx);
}

extern "C" void kernel_launch(void* const* d_in, const int* in_sizes, int n_in,
                              void* d_out, int out_size, void* d_ws, size_t ws_size,
                              hipStream_t stream)
{
    const float* in  = (const float*)d_in[0];
    const int*   dx  = (const int*)d_in[1];
    const int*   dy  = (const int*)d_in[2];
    float*       out = (float*)d_out;

    // total float4s = 128*512*128 = 8,388,608 ; /256 threads = 32768 blocks
    const int total4 = TB * TH * W4;
    dim3 grid(total4 / 256), block(256);
    TranslationLayer_63350767616318_kernel<<<grid, block, 0, stream>>>(in, dx, dy, out);
}